// Round 18
// baseline (5363.350 us; speedup 1.0000x reference)
//
#include <hip/hip_runtime.h>

#define T_STEPS 8192
#define BATCH   128
#define HID     96
#define BT      4                  // batch tile per block
#define NBLK    (BATCH / BT)       // 32 blocks

typedef unsigned int u32;
typedef u32   u32x4 __attribute__((ext_vector_type(4)));
typedef float f32x4 __attribute__((ext_vector_type(4)));
typedef __fp16 h2_t __attribute__((ext_vector_type(2)));

#define L2E 1.4426950408889634f
#define K2  2.8853900817779268f   // 2*log2(e)

__device__ __forceinline__ u32 pk2(float a, float b) {
    return __builtin_bit_cast(u32, __builtin_amdgcn_cvt_pkrtz(a, b));
}
// preacts arrive PRE-SCALED by log2e (2log2e for g/cell): exp2 direct
__device__ __forceinline__ float sig2(float v) {
    return __builtin_amdgcn_rcpf(1.0f + __builtin_amdgcn_exp2f(-v));
}
__device__ __forceinline__ float tanh2(float v) {
    return fmaf(2.0f, __builtin_amdgcn_rcpf(1.0f + __builtin_amdgcn_exp2f(-v)), -1.0f);
}

#define MFMA(ACC, AF, BF) \
    asm("v_mfma_f32_16x16x32_f16 %0, %1, %2, %0" : "+v"(ACC) : "v"(AF), "a"(BF))

// LDS-only barrier (R15-R17 proven)
#define LBAR() asm volatile("s_waitcnt lgkmcnt(0)\n\ts_barrier" ::: "memory")

// ---- prepack W_hh -> f16 B-frags for the 3-wave layout ----
// thread tid (0..191): u=tid>>6, l=tid&63. frag f = tau*3+s, tau = (gate g)| (half)<<2:
// n = g*96 + u*32 + (tau>>2)*16 + (l&15); k = s*32 + ((l>>4)&3)*8 + 2r{,+1}.
__global__ void prepack_kernel(const float* __restrict__ W_hh, u32* __restrict__ wpk) {
    const int i = blockIdx.x * blockDim.x + threadIdx.x;   // over 192*96 u32
    if (i < 192 * 96) {
        const int tid = i / 96, rem = i % 96;
        const int f = rem >> 2, r = rem & 3;
        const int u = tid >> 6, l = tid & 63;
        const int tau = f / 3, s = f % 3;
        const int g = tau & 3, hf = tau >> 2;
        const int n = g * HID + u * 32 + hf * 16 + (l & 15);
        const int k = s * 32 + ((l >> 4) & 3) * 8 + 2 * r;
        const float sc = (g == 2) ? K2 : L2E;
        wpk[i] = pk2(W_hh[n * HID + k] * sc, W_hh[n * HID + k + 1] * sc);
    }
}

__global__ __attribute__((amdgpu_flat_work_group_size(192, 192), amdgpu_waves_per_eu(1, 2)))
void lstm_mfma_kernel(const float* __restrict__ x,
                      const float* __restrict__ W_ih,
                      const float* __restrict__ b_ih,
                      const float* __restrict__ b_hh,
                      const float* __restrict__ W_fc,
                      const float* __restrict__ b_fc,
                      const u32x4* __restrict__ wpk4,
                      float* __restrict__ out)
{
    const int bo  = blockIdx.x * BT;
    const int tid = threadIdx.x;            // 0..191: 3 worker waves, FC folded in
    const int l = tid & 63, u = tid >> 6;
    const int lg = l >> 4, li = l & 15;

    // h by k-tile: [parity][ktile][batch][stride 80 f16] -> every A-read <=2-way banked
    __shared__ __align__(16) __fp16 harr[2][3][BT][80];
    __shared__ __align__(16) float  xs[2][BT];
    __shared__ __align__(16) float  fcp[2][BT][3];   // FC partials per wave

    for (int i = tid; i < 2 * 3 * BT * 80 / 2; i += 192) ((u32*)harr)[i] = 0u;
    if (tid < 2 * BT * 3) ((float*)fcp)[tid] = 0.0f;
    if (tid < BT) xs[0][tid] = x[bo + tid];

    const int jA = u * 32 + li;             // this lane's units
    const int jB = jA + 16;

    // B-frags: 24 x u32x4, load once, pin to AGPRs (R12-proven residency)
    const u32x4* wp = wpk4 + tid * 24;
    u32x4 bf0  = wp[0],  bf1  = wp[1],  bf2  = wp[2],  bf3  = wp[3];
    u32x4 bf4  = wp[4],  bf5  = wp[5],  bf6  = wp[6],  bf7  = wp[7];
    u32x4 bf8  = wp[8],  bf9  = wp[9],  bf10 = wp[10], bf11 = wp[11];
    u32x4 bf12 = wp[12], bf13 = wp[13], bf14 = wp[14], bf15 = wp[15];
    u32x4 bf16 = wp[16], bf17 = wp[17], bf18 = wp[18], bf19 = wp[19];
    u32x4 bf20 = wp[20], bf21 = wp[21], bf22 = wp[22], bf23 = wp[23];
    asm volatile("" : "+a"(bf0));  asm volatile("" : "+a"(bf1));
    asm volatile("" : "+a"(bf2));  asm volatile("" : "+a"(bf3));
    asm volatile("" : "+a"(bf4));  asm volatile("" : "+a"(bf5));
    asm volatile("" : "+a"(bf6));  asm volatile("" : "+a"(bf7));
    asm volatile("" : "+a"(bf8));  asm volatile("" : "+a"(bf9));
    asm volatile("" : "+a"(bf10)); asm volatile("" : "+a"(bf11));
    asm volatile("" : "+a"(bf12)); asm volatile("" : "+a"(bf13));
    asm volatile("" : "+a"(bf14)); asm volatile("" : "+a"(bf15));
    asm volatile("" : "+a"(bf16)); asm volatile("" : "+a"(bf17));
    asm volatile("" : "+a"(bf18)); asm volatile("" : "+a"(bf19));
    asm volatile("" : "+a"(bf20)); asm volatile("" : "+a"(bf21));
    asm volatile("" : "+a"(bf22)); asm volatile("" : "+a"(bf23));

    // x-weights / biases for jA and jB, prescaled (i,f,o: log2e; g: 2log2e)
    f32x4 wihA = { W_ih[0*HID+jA] * L2E, W_ih[1*HID+jA] * L2E,
                   W_ih[2*HID+jA] * K2,  W_ih[3*HID+jA] * L2E };
    f32x4 bsA  = { (b_ih[0*HID+jA] + b_hh[0*HID+jA]) * L2E,
                   (b_ih[1*HID+jA] + b_hh[1*HID+jA]) * L2E,
                   (b_ih[2*HID+jA] + b_hh[2*HID+jA]) * K2,
                   (b_ih[3*HID+jA] + b_hh[3*HID+jA]) * L2E };
    f32x4 wihB = { W_ih[0*HID+jB] * L2E, W_ih[1*HID+jB] * L2E,
                   W_ih[2*HID+jB] * K2,  W_ih[3*HID+jB] * L2E };
    f32x4 bsB  = { (b_ih[0*HID+jB] + b_hh[0*HID+jB]) * L2E,
                   (b_ih[1*HID+jB] + b_hh[1*HID+jB]) * L2E,
                   (b_ih[2*HID+jB] + b_hh[2*HID+jB]) * K2,
                   (b_ih[3*HID+jB] + b_hh[3*HID+jB]) * L2E };
    asm volatile("" : "+v"(wihA)); asm volatile("" : "+v"(bsA));
    asm volatile("" : "+v"(wihB)); asm volatile("" : "+v"(bsB));
    const float wfcA = W_fc[jA], wfcB = W_fc[jB];
    const float bfc  = b_fc[0];

    float cA = 0.0f, cB = 0.0f;             // scaled cell state (batch lg, units jA/jB)

    // out/x duty: wave 0, li==0 lanes (one per batch)
    const bool emitter = (u == 0) && (li == 0);
    float xO = 0.f, xC = 0.f, xP = 0.f;
    if (emitter) { xC = x[bo + lg]; xP = x[BATCH + bo + lg]; }
    __syncthreads();

    for (int t = 0; t < T_STEPS; ++t) {
        const int cb = t & 1, nb = cb ^ 1;

        const float xm = xs[cb][lg];
        // A-frags: lane l reads h[batch (l&15)>>2][k = lg*8 + s*32 .. +8]
        const int ar = li >> 2;
        const u32x4 a0 = *(const u32x4*)&harr[cb][0][ar][lg * 8];
        const u32x4 a1 = *(const u32x4*)&harr[cb][1][ar][lg * 8];
        const u32x4 a2 = *(const u32x4*)&harr[cb][2][ar][lg * 8];

        // emit out[t-1] + x shift (4 lanes of wave 0, fire-and-forget store)
        if (emitter) {
            if (t > 0) {
                const float* fp = fcp[cb][lg];
                out[(t - 1) * BATCH + bo + lg] = (fp[0] + fp[1] + fp[2]) + bfc + xO;
            }
            xs[nb][lg] = xP;
            xO = xC; xC = xP;
            const int tn = (t + 2 < T_STEPS) ? (t + 2) : (T_STEPS - 1);
            xP = x[tn * BATCH + bo + lg];
        }

        // C-init: all acc rows carry batch lg -> splat per-gate e
        const float eA0 = fmaf(xm, wihA[0], bsA[0]), eA1 = fmaf(xm, wihA[1], bsA[1]);
        const float eA2 = fmaf(xm, wihA[2], bsA[2]), eA3 = fmaf(xm, wihA[3], bsA[3]);
        const float eB0 = fmaf(xm, wihB[0], bsB[0]), eB1 = fmaf(xm, wihB[1], bsB[1]);
        const float eB2 = fmaf(xm, wihB[2], bsB[2]), eB3 = fmaf(xm, wihB[3], bsB[3]);
        f32x4 acc0 = {eA0, eA0, eA0, eA0}, acc1 = {eA1, eA1, eA1, eA1};
        f32x4 acc2 = {eA2, eA2, eA2, eA2}, acc3 = {eA3, eA3, eA3, eA3};
        f32x4 acc4 = {eB0, eB0, eB0, eB0}, acc5 = {eB1, eB1, eB1, eB1};
        f32x4 acc6 = {eB2, eB2, eB2, eB2}, acc7 = {eB3, eB3, eB3, eB3};

        // 24 MFMA: 8 independent chains of depth 3
        MFMA(acc0, a0, bf0);  MFMA(acc1, a0, bf3);  MFMA(acc2, a0, bf6);  MFMA(acc3, a0, bf9);
        MFMA(acc4, a0, bf12); MFMA(acc5, a0, bf15); MFMA(acc6, a0, bf18); MFMA(acc7, a0, bf21);
        MFMA(acc0, a1, bf1);  MFMA(acc1, a1, bf4);  MFMA(acc2, a1, bf7);  MFMA(acc3, a1, bf10);
        MFMA(acc4, a1, bf13); MFMA(acc5, a1, bf16); MFMA(acc6, a1, bf19); MFMA(acc7, a1, bf22);
        MFMA(acc0, a2, bf2);  MFMA(acc1, a2, bf5);  MFMA(acc2, a2, bf8);  MFMA(acc3, a2, bf11);
        MFMA(acc4, a2, bf14); MFMA(acc5, a2, bf17); MFMA(acc6, a2, bf20); MFMA(acc7, a2, bf23);
        asm volatile("s_nop 7\n\ts_nop 7");         // MFMA->VALU hazard guard

        // epilogue: 2 updates/lane, static reg index 0 (row lg*4 -> batch lg)
        const float giA = sig2(acc0[0]), gfA = sig2(acc1[0]);
        const float ggA = tanh2(acc2[0]), goA = sig2(acc3[0]);
        cA = fmaf(gfA, cA, giA * ggA * K2);
        const float hnA = goA * tanh2(cA);
        const float giB = sig2(acc4[0]), gfB = sig2(acc5[0]);
        const float ggB = tanh2(acc6[0]), goB = sig2(acc7[0]);
        cB = fmaf(gfB, cB, giB * ggB * K2);
        const float hnB = goB * tanh2(cB);

        // h writes: array u, offsets li / li+16 -> conflict-free b16 per instr
        harr[nb][u][lg][li]      = (__fp16)hnA;
        harr[nb][u][lg][li + 16] = (__fp16)hnB;

        // folded FC: reduce hnA*wfcA + hnB*wfcB over the 16 lanes of this batch
        float p = fmaf(hnB, wfcB, hnA * wfcA);
        p += __shfl_xor(p, 1); p += __shfl_xor(p, 2);
        p += __shfl_xor(p, 4); p += __shfl_xor(p, 8);
        if (li == 0) fcp[nb][lg][u] = p;

        LBAR();
    }

    // tail: out[T-1] (fcp parity 0 after last step; xO = x[T-1])
    if (emitter) {
        const float* fp = fcp[T_STEPS & 1][lg];
        out[(T_STEPS - 1) * BATCH + bo + lg] = (fp[0] + fp[1] + fp[2]) + bfc + xO;
    }
}

extern "C" void kernel_launch(void* const* d_in, const int* in_sizes, int n_in,
                              void* d_out, int out_size, void* d_ws, size_t ws_size,
                              hipStream_t stream) {
    (void)in_sizes; (void)n_in; (void)out_size; (void)ws_size;
    const float* x    = (const float*)d_in[0];
    const float* W_ih = (const float*)d_in[1];
    const float* W_hh = (const float*)d_in[2];
    const float* b_ih = (const float*)d_in[3];
    const float* b_hh = (const float*)d_in[4];
    const float* W_fc = (const float*)d_in[5];
    const float* b_fc = (const float*)d_in[6];
    float* out = (float*)d_out;
    u32* wpk = (u32*)d_ws;                          // 192*96 u32 = 73728 B

    prepack_kernel<<<dim3((192 * 96 + 255) / 256), dim3(256), 0, stream>>>(W_hh, wpk);

    lstm_mfma_kernel<<<dim3(NBLK), dim3(192), 0, stream>>>(
        x, W_ih, b_ih, b_hh, W_fc, b_fc, (const u32x4*)wpk, out);
}

// Round 19
// 4175.216 us; speedup vs baseline: 1.2846x; 1.2846x over previous
//
#include <hip/hip_runtime.h>

#define T_STEPS 8192
#define BATCH   128
#define HID     96
#define BT      4                  // batch tile per block
#define NBLK    (BATCH / BT)       // 32 blocks

typedef unsigned int u32;
typedef u32   u32x4 __attribute__((ext_vector_type(4)));
typedef float f32x4 __attribute__((ext_vector_type(4)));
typedef __fp16 h2_t __attribute__((ext_vector_type(2)));

#define L2E 1.4426950408889634f
#define K2  2.8853900817779268f   // 2*log2(e)

__device__ __forceinline__ u32 pk2(float a, float b) {
    return __builtin_bit_cast(u32, __builtin_amdgcn_cvt_pkrtz(a, b));
}
__device__ __forceinline__ float fdot2u(u32 w, u32 h, float acc) {
    return __builtin_amdgcn_fdot2(__builtin_bit_cast(h2_t, w),
                                  __builtin_bit_cast(h2_t, h), acc, false);
}
// preacts arrive PRE-SCALED by log2e (2log2e for g/cell): exp2 direct
__device__ __forceinline__ float sig2(float v) {
    return __builtin_amdgcn_rcpf(1.0f + __builtin_amdgcn_exp2f(-v));
}
__device__ __forceinline__ float tanh2(float v) {
    return fmaf(2.0f, __builtin_amdgcn_rcpf(1.0f + __builtin_amdgcn_exp2f(-v)), -1.0f);
}

#define MFMA(ACC, AF, BF) \
    asm("v_mfma_f32_16x16x32_f16 %0, %1, %2, %0" : "+v"(ACC) : "v"(AF), "a"(BF))

// LDS-only barrier (R15-R17 proven)
#define LBAR() asm volatile("s_waitcnt lgkmcnt(0)\n\ts_barrier" ::: "memory")

// ---- prepack W_hh -> f16 MFMA B-frags (R12-verified mapping) + exp2 prescale ----
__global__ void prepack_kernel(const float* __restrict__ W_hh, u32* __restrict__ wpk) {
    const int i = blockIdx.x * blockDim.x + threadIdx.x;
    if (i < 384 * 48) {
        const int r   = i & 3;
        const int u4  = i >> 2;
        const int tid = u4 / 12;
        const int f   = u4 % 12;
        const int g = f / 3, s = f % 3;
        const int l = tid & 63, u = tid >> 6;
        const int n = g * HID + u * 16 + (l & 15);
        const int k = s * 32 + ((l >> 4) & 3) * 8 + 2 * r;
        const float sc = (g == 2) ? K2 : L2E;
        wpk[i] = pk2(W_hh[n * HID + k] * sc, W_hh[n * HID + k + 1] * sc);
    }
}

__global__ __attribute__((amdgpu_flat_work_group_size(448, 448), amdgpu_waves_per_eu(1, 2)))
void lstm_mfma_kernel(const float* __restrict__ x,
                      const float* __restrict__ W_ih,
                      const float* __restrict__ b_ih,
                      const float* __restrict__ b_hh,
                      const float* __restrict__ W_fc,
                      const float* __restrict__ b_fc,
                      const u32x4* __restrict__ wpk4,
                      float* __restrict__ out)
{
    const int bo  = blockIdx.x * BT;
    const int tid = threadIdx.x;            // waves 0-5 workers, wave 6 FC
    const int l = tid & 63, u = tid >> 6;
    const bool isW = tid < 384;
    const int lg = l >> 4;                  // worker: k-subgroup / epilogue batch

    __shared__ __align__(16) __fp16 hbuf[2][BT][104];   // h state, row-pad 104
    __shared__ __align__(16) float  xs[2][BT];
    __shared__ __align__(16) float  fcp[BT][4];         // FC 4-way partials (same-step)

    for (int i = tid; i < 2 * BT * 104 / 2; i += 448) ((u32*)hbuf)[i] = 0u;
    if (tid < BT * 4) ((float*)fcp)[tid] = 0.0f;
    if (tid < BT) xs[0][tid] = x[bo + tid];

    const int jw = isW ? (u * 16 + (l & 15)) : 0;

    // B-frags: load once, pin to AGPRs (R12-proven residency)
    const u32x4* wp = wpk4 + (isW ? tid * 12 : 0);
    u32x4 b0 = wp[0], b1 = wp[1], b2  = wp[2],  b3  = wp[3];
    u32x4 b4 = wp[4], b5 = wp[5], b6  = wp[6],  b7  = wp[7];
    u32x4 b8 = wp[8], b9 = wp[9], b10 = wp[10], b11 = wp[11];
    asm volatile("" : "+a"(b0));  asm volatile("" : "+a"(b1));
    asm volatile("" : "+a"(b2));  asm volatile("" : "+a"(b3));
    asm volatile("" : "+a"(b4));  asm volatile("" : "+a"(b5));
    asm volatile("" : "+a"(b6));  asm volatile("" : "+a"(b7));
    asm volatile("" : "+a"(b8));  asm volatile("" : "+a"(b9));
    asm volatile("" : "+a"(b10)); asm volatile("" : "+a"(b11));

    // x-weights / biases, prescaled per gate (i,f,o: log2e; g: 2log2e)
    f32x4 wih4 = { W_ih[0*HID+jw] * L2E, W_ih[1*HID+jw] * L2E,
                   W_ih[2*HID+jw] * K2,  W_ih[3*HID+jw] * L2E };
    f32x4 bs4  = { (b_ih[0*HID+jw] + b_hh[0*HID+jw]) * L2E,
                   (b_ih[1*HID+jw] + b_hh[1*HID+jw]) * L2E,
                   (b_ih[2*HID+jw] + b_hh[2*HID+jw]) * K2,
                   (b_ih[3*HID+jw] + b_hh[3*HID+jw]) * L2E };
    asm volatile("" : "+v"(wih4)); asm volatile("" : "+v"(bs4));
    const float bfc = b_fc[0];

    // FC wave: fm = l>>4 (batch), fp = l&15 (col group of 6 f16)
    //   -> reduce levels xor1/xor2 are DPP quad_perm (VALU), then 4-slot LDS
    //      partials summed SAME STEP by the fp==0 lane after an intra-wave wait.
    const int fm = l >> 4, fp = l & 15;
    u32 wf0 = 0, wf1 = 0, wf2 = 0;
    if (!isW) {
        wf0 = pk2(W_fc[fp*6+0], W_fc[fp*6+1]);
        wf1 = pk2(W_fc[fp*6+2], W_fc[fp*6+3]);
        wf2 = pk2(W_fc[fp*6+4], W_fc[fp*6+5]);
    }

    float c = 0.0f;                         // scaled cell state, batch lg, unit jw

    // FC x shift-chain: xO=x[t-1], xC=x[t], xP=x[t+1]   (fp==0 lanes)
    float xO = 0.f, xC = 0.f, xP = 0.f;
    if (!isW) { xC = x[bo + fm]; xP = x[BATCH + bo + fm]; }
    __syncthreads();

    for (int t = 0; t < T_STEPS; ++t) {
        const int cb = t & 1, nb = cb ^ 1;
        if (isW) {
            const float xm = xs[cb][lg];    // this lane's batch x (broadcast read)
            // A-frags: lane l holds A[row l&15][k=lg*8+e]; rowbatch(rho)=rho>>2
            const __fp16* hrow = &hbuf[cb][(l & 15) >> 2][lg * 8];
            const u32x4 a0 = *(const u32x4*)(hrow);
            const u32x4 a1 = *(const u32x4*)(hrow + 32);
            const u32x4 a2 = *(const u32x4*)(hrow + 64);

            // C-init: all 4 acc rows = batch lg -> splat e_g
            const float e0 = fmaf(xm, wih4[0], bs4[0]);
            const float e1 = fmaf(xm, wih4[1], bs4[1]);
            const float e2 = fmaf(xm, wih4[2], bs4[2]);
            const float e3 = fmaf(xm, wih4[3], bs4[3]);
            f32x4 acc0 = {e0, e0, e0, e0};
            f32x4 acc1 = {e1, e1, e1, e1};
            f32x4 acc2 = {e2, e2, e2, e2};
            f32x4 acc3 = {e3, e3, e3, e3};

            MFMA(acc0, a0, b0); MFMA(acc1, a0, b3); MFMA(acc2, a0, b6); MFMA(acc3, a0, b9);
            MFMA(acc0, a1, b1); MFMA(acc1, a1, b4); MFMA(acc2, a1, b7); MFMA(acc3, a1, b10);
            MFMA(acc0, a2, b2); MFMA(acc1, a2, b5); MFMA(acc2, a2, b8); MFMA(acc3, a2, b11);
            asm volatile("s_nop 7\n\ts_nop 7");     // MFMA->VALU hazard guard

            // epilogue: ONE update per lane (batch lg, unit jw), static reg index 0
            const float gi = sig2(acc0[0]);
            const float gf = sig2(acc1[0]);
            const float gg = tanh2(acc2[0]);
            const float go = sig2(acc3[0]);
            c = fmaf(gf, c, gi * gg * K2);
            const float hn = go * tanh2(c);
            hbuf[nb][lg][jw] = (__fp16)hn;
        } else {
            if (t > 0) {
                // h_t dot W_fc: lane (fm, fp) covers 6 f16 cols
                const u32* hp = (const u32*)&hbuf[cb][fm][0] + fp * 3;
                const u32 hA = hp[0], hB = hp[1], hC = hp[2];
                float s0 = fdot2u(wf0, hA, 0.0f);
                float s1 = fdot2u(wf1, hB, 0.0f);
                float s2 = fdot2u(wf2, hC, 0.0f);
                float p = (s0 + s1) + s2;
                p += __shfl_xor(p, 1);      // DPP quad_perm
                p += __shfl_xor(p, 2);      // DPP quad_perm
                if ((fp & 3) == 0) fcp[fm][fp >> 2] = p;
                asm volatile("s_waitcnt lgkmcnt(0)" ::: "memory");  // intra-wave
                if (fp == 0) {
                    const float s = (fcp[fm][0] + fcp[fm][1]) + (fcp[fm][2] + fcp[fm][3]);
                    out[(t - 1) * BATCH + bo + fm] = s + bfc + xO;  // fire-and-forget
                }
            }
            if (fp == 0) xs[nb][fm] = xP;           // stage x[t+1]
            xO = xC; xC = xP;                       // shift chain
            const int tn = (t + 2 < T_STEPS) ? (t + 2) : (T_STEPS - 1);
            xP = x[tn * BATCH + bo + fm];
        }
        LBAR();
    }

    if (!isW) {   // tail: out[T-1] from h_T (hbuf[0]); xO = x[T-1]
        const u32* hp = (const u32*)&hbuf[T_STEPS & 1][fm][0] + fp * 3;
        const u32 hA = hp[0], hB = hp[1], hC = hp[2];
        float s0 = fdot2u(wf0, hA, 0.0f);
        float s1 = fdot2u(wf1, hB, 0.0f);
        float s2 = fdot2u(wf2, hC, 0.0f);
        float p = (s0 + s1) + s2;
        p += __shfl_xor(p, 1);
        p += __shfl_xor(p, 2);
        if ((fp & 3) == 0) fcp[fm][fp >> 2] = p;
        asm volatile("s_waitcnt lgkmcnt(0)" ::: "memory");
        if (fp == 0) {
            const float s = (fcp[fm][0] + fcp[fm][1]) + (fcp[fm][2] + fcp[fm][3]);
            out[(T_STEPS - 1) * BATCH + bo + fm] = s + bfc + xO;
        }
    }
}

extern "C" void kernel_launch(void* const* d_in, const int* in_sizes, int n_in,
                              void* d_out, int out_size, void* d_ws, size_t ws_size,
                              hipStream_t stream) {
    (void)in_sizes; (void)n_in; (void)out_size; (void)ws_size;
    const float* x    = (const float*)d_in[0];
    const float* W_ih = (const float*)d_in[1];
    const float* W_hh = (const float*)d_in[2];
    const float* b_ih = (const float*)d_in[3];
    const float* b_hh = (const float*)d_in[4];
    const float* W_fc = (const float*)d_in[5];
    const float* b_fc = (const float*)d_in[6];
    float* out = (float*)d_out;
    u32* wpk = (u32*)d_ws;                          // 384*48 u32 = 73728 B

    prepack_kernel<<<dim3((384 * 48 + 255) / 256), dim3(256), 0, stream>>>(W_hh, wpk);

    lstm_mfma_kernel<<<dim3(NBLK), dim3(448), 0, stream>>>(
        x, W_ih, b_ih, b_hh, W_fc, b_fc, (const u32x4*)wpk, out);
}

// Round 20
// 3661.010 us; speedup vs baseline: 1.4650x; 1.1405x over previous
//
#include <hip/hip_runtime.h>

#define T_STEPS 8192
#define BATCH   128
#define HID     96
#define BT      4                  // batch tile per block
#define NBLK    (BATCH / BT)       // 32 blocks

typedef unsigned int u32;
typedef u32   u32x4 __attribute__((ext_vector_type(4)));
typedef float f32x4 __attribute__((ext_vector_type(4)));
typedef __fp16 h2_t __attribute__((ext_vector_type(2)));

#define L2E 1.4426950408889634f
#define K2  2.8853900817779268f   // 2*log2(e)

__device__ __forceinline__ u32 pk2(float a, float b) {
    return __builtin_bit_cast(u32, __builtin_amdgcn_cvt_pkrtz(a, b));
}
__device__ __forceinline__ float fdot2u(u32 w, u32 h, float acc) {
    return __builtin_amdgcn_fdot2(__builtin_bit_cast(h2_t, w),
                                  __builtin_bit_cast(h2_t, h), acc, false);
}
// preacts arrive PRE-SCALED by log2e (2log2e for g/cell): exp2 direct
__device__ __forceinline__ float sig2(float v) {
    return __builtin_amdgcn_rcpf(1.0f + __builtin_amdgcn_exp2f(-v));
}
__device__ __forceinline__ float tanh2(float v) {
    return fmaf(2.0f, __builtin_amdgcn_rcpf(1.0f + __builtin_amdgcn_exp2f(-v)), -1.0f);
}

// chained MFMA: D = A*B + D
#define MFMA(ACC, AF, BF) \
    asm("v_mfma_f32_16x16x32_f16 %0, %1, %2, %0" : "+v"(ACC) : "v"(AF), "a"(BF))
// fresh-accumulator MFMA: D = A*B + Z (Z = pinned zero quad; kills C-init splats)
#define MFMA_Z(D, AF, BF, Z) \
    asm("v_mfma_f32_16x16x32_f16 %0, %1, %2, %3" : "=v"(D) : "v"(AF), "a"(BF), "v"(Z))

// LDS-only barrier (R15-R19 proven)
#define LBAR() asm volatile("s_waitcnt lgkmcnt(0)\n\ts_barrier" ::: "memory")

// ---- prepack W_hh -> f16 MFMA B-frags (R12-verified mapping) + exp2 prescale ----
__global__ void prepack_kernel(const float* __restrict__ W_hh, u32* __restrict__ wpk) {
    const int i = blockIdx.x * blockDim.x + threadIdx.x;
    if (i < 384 * 48) {
        const int r   = i & 3;
        const int u4  = i >> 2;
        const int tid = u4 / 12;
        const int f   = u4 % 12;
        const int g = f / 3, s = f % 3;
        const int l = tid & 63, u = tid >> 6;
        const int n = g * HID + u * 16 + (l & 15);
        const int k = s * 32 + ((l >> 4) & 3) * 8 + 2 * r;
        const float sc = (g == 2) ? K2 : L2E;
        wpk[i] = pk2(W_hh[n * HID + k] * sc, W_hh[n * HID + k + 1] * sc);
    }
}

__global__ __attribute__((amdgpu_flat_work_group_size(448, 448), amdgpu_waves_per_eu(1, 2)))
void lstm_mfma_kernel(const float* __restrict__ x,
                      const float* __restrict__ W_ih,
                      const float* __restrict__ b_ih,
                      const float* __restrict__ b_hh,
                      const float* __restrict__ W_fc,
                      const float* __restrict__ b_fc,
                      const u32x4* __restrict__ wpk4,
                      float* __restrict__ out)
{
    const int bo  = blockIdx.x * BT;
    const int tid = threadIdx.x;            // waves 0-5 workers, wave 6 FC
    const int l = tid & 63, u = tid >> 6;
    const bool isW = tid < 384;
    const int lg = l >> 4;                  // worker: k-subgroup / epilogue batch

    __shared__ __align__(16) __fp16 hbuf[2][BT][104];   // h state, row-pad 104
    __shared__ __align__(16) float  xs[2][BT];
    __shared__ __align__(16) float  fcp[BT][4];         // FC 4-way partials (same-step)

    for (int i = tid; i < 2 * BT * 104 / 2; i += 448) ((u32*)hbuf)[i] = 0u;
    if (tid < BT * 4) ((float*)fcp)[tid] = 0.0f;
    if (tid < BT) xs[0][tid] = x[bo + tid];

    const int jw = isW ? (u * 16 + (l & 15)) : 0;

    // B-frags: load once, pin to AGPRs (R12-proven residency)
    const u32x4* wp = wpk4 + (isW ? tid * 12 : 0);
    u32x4 b0 = wp[0], b1 = wp[1], b2  = wp[2],  b3  = wp[3];
    u32x4 b4 = wp[4], b5 = wp[5], b6  = wp[6],  b7  = wp[7];
    u32x4 b8 = wp[8], b9 = wp[9], b10 = wp[10], b11 = wp[11];
    asm volatile("" : "+a"(b0));  asm volatile("" : "+a"(b1));
    asm volatile("" : "+a"(b2));  asm volatile("" : "+a"(b3));
    asm volatile("" : "+a"(b4));  asm volatile("" : "+a"(b5));
    asm volatile("" : "+a"(b6));  asm volatile("" : "+a"(b7));
    asm volatile("" : "+a"(b8));  asm volatile("" : "+a"(b9));
    asm volatile("" : "+a"(b10)); asm volatile("" : "+a"(b11));

    // x-weights / biases, prescaled per gate (i,f,o: log2e; g: 2log2e)
    f32x4 wih4 = { W_ih[0*HID+jw] * L2E, W_ih[1*HID+jw] * L2E,
                   W_ih[2*HID+jw] * K2,  W_ih[3*HID+jw] * L2E };
    f32x4 bs4  = { (b_ih[0*HID+jw] + b_hh[0*HID+jw]) * L2E,
                   (b_ih[1*HID+jw] + b_hh[1*HID+jw]) * L2E,
                   (b_ih[2*HID+jw] + b_hh[2*HID+jw]) * K2,
                   (b_ih[3*HID+jw] + b_hh[3*HID+jw]) * L2E };
    asm volatile("" : "+v"(wih4)); asm volatile("" : "+v"(bs4));
    const float bfc = b_fc[0];

    // pinned zero quad: fresh-acc MFMA C-operand (pin stops MachineSink re-zeroing)
    f32x4 zq = {0.f, 0.f, 0.f, 0.f};
    asm volatile("" : "+v"(zq));

    // FC wave: fm = l>>4 (batch), fp = l&15 (col group of 6 f16) -- R19 layout
    const int fm = l >> 4, fp = l & 15;
    u32 wf0 = 0, wf1 = 0, wf2 = 0;
    if (!isW) {
        wf0 = pk2(W_fc[fp*6+0], W_fc[fp*6+1]);
        wf1 = pk2(W_fc[fp*6+2], W_fc[fp*6+3]);
        wf2 = pk2(W_fc[fp*6+4], W_fc[fp*6+5]);
    }

    float c = 0.0f;                         // scaled cell state, batch lg, unit jw

    // parity-constant LDS pointers (unroll-2: no per-step cb/nb address math)
    const __fp16* hr0 = &hbuf[0][(l & 15) >> 2][lg * 8];   // A-frag base, cb=0
    const __fp16* hr1 = &hbuf[1][(l & 15) >> 2][lg * 8];   // A-frag base, cb=1
    __fp16* hw0 = &hbuf[1][lg][jw];                        // h write, cb=0 (nb=1)
    __fp16* hw1 = &hbuf[0][lg][jw];                        // h write, cb=1 (nb=0)
    const u32* fr0 = (const u32*)&hbuf[0][fm][0] + fp * 3; // FC read, cb=0
    const u32* fr1 = (const u32*)&hbuf[1][fm][0] + fp * 3; // FC read, cb=1

    // FC x shift-chain: xO=x[t-1], xC=x[t], xP=x[t+1]
    float xO = 0.f, xC = 0.f, xP = 0.f;
    if (!isW) { xC = x[bo + fm]; xP = x[BATCH + bo + fm]; }
    __syncthreads();

#define WORK_BODY(P)                                                              \
    {                                                                             \
        const float xm = xs[P][lg];                                               \
        const __fp16* hr = (P) ? hr1 : hr0;                                       \
        const u32x4 a0 = *(const u32x4*)(hr);                                     \
        const u32x4 a1 = *(const u32x4*)(hr + 32);                                \
        const u32x4 a2 = *(const u32x4*)(hr + 64);                                \
        const float e0 = fmaf(xm, wih4[0], bs4[0]);                               \
        const float e1 = fmaf(xm, wih4[1], bs4[1]);                               \
        const float e2 = fmaf(xm, wih4[2], bs4[2]);                               \
        const float e3 = fmaf(xm, wih4[3], bs4[3]);                               \
        f32x4 acc0, acc1, acc2, acc3;                                             \
        MFMA_Z(acc0, a0, b0, zq); MFMA_Z(acc1, a0, b3, zq);                       \
        MFMA_Z(acc2, a0, b6, zq); MFMA_Z(acc3, a0, b9, zq);                       \
        MFMA(acc0, a1, b1);  MFMA(acc1, a1, b4);                                  \
        MFMA(acc2, a1, b7);  MFMA(acc3, a1, b10);                                 \
        MFMA(acc0, a2, b2);  MFMA(acc1, a2, b5);                                  \
        MFMA(acc2, a2, b8);  MFMA(acc3, a2, b11);                                 \
        asm volatile("s_nop 7");             /* acc0 last write 3 MFMAs back */   \
        const float gi = sig2(acc0[0] + e0);                                      \
        const float gf = sig2(acc1[0] + e1);                                      \
        const float gg = tanh2(acc2[0] + e2);                                     \
        const float go = sig2(acc3[0] + e3);                                      \
        c = fmaf(gf, c, gi * gg * K2);                                            \
        const float hn = go * tanh2(c);                                           \
        *((P) ? hw1 : hw0) = (__fp16)hn;                                          \
    }

#define FC_BODY(P, T)                                                             \
    {                                                                             \
        if ((T) > 0) {                                                            \
            const u32* hp = (P) ? fr1 : fr0;                                      \
            const u32 hA = hp[0], hB = hp[1], hC = hp[2];                         \
            float s0 = fdot2u(wf0, hA, 0.0f);                                     \
            float s1 = fdot2u(wf1, hB, 0.0f);                                     \
            float s2 = fdot2u(wf2, hC, 0.0f);                                     \
            float p = (s0 + s1) + s2;                                             \
            p += __shfl_xor(p, 1);          /* DPP quad_perm */                   \
            p += __shfl_xor(p, 2);          /* DPP quad_perm */                   \
            if ((fp & 3) == 0) fcp[fm][fp >> 2] = p;                              \
            asm volatile("s_waitcnt lgkmcnt(0)" ::: "memory");                    \
            if (fp == 0) {                                                        \
                const float s = (fcp[fm][0] + fcp[fm][1]) + (fcp[fm][2] + fcp[fm][3]); \
                out[((T) - 1) * BATCH + bo + fm] = s + bfc + xO;                  \
            }                                                                     \
        }                                                                         \
        if (fp == 0) xs[(P) ^ 1][fm] = xP;                                        \
        xO = xC; xC = xP;                                                         \
        const int tn = ((T) + 2 < T_STEPS) ? ((T) + 2) : (T_STEPS - 1);           \
        xP = x[tn * BATCH + bo + fm];                                             \
    }

    for (int t = 0; t < T_STEPS; t += 2) {
        if (isW) WORK_BODY(0) else FC_BODY(0, t)
        LBAR();
        if (isW) WORK_BODY(1) else FC_BODY(1, t + 1)
        LBAR();
    }

    if (!isW) {   // tail: out[T-1] from h_T (hbuf[0]); xO = x[T-1]
        const u32 hA = fr0[0], hB = fr0[1], hC = fr0[2];
        float s0 = fdot2u(wf0, hA, 0.0f);
        float s1 = fdot2u(wf1, hB, 0.0f);
        float s2 = fdot2u(wf2, hC, 0.0f);
        float p = (s0 + s1) + s2;
        p += __shfl_xor(p, 1);
        p += __shfl_xor(p, 2);
        if ((fp & 3) == 0) fcp[fm][fp >> 2] = p;
        asm volatile("s_waitcnt lgkmcnt(0)" ::: "memory");
        if (fp == 0) {
            const float s = (fcp[fm][0] + fcp[fm][1]) + (fcp[fm][2] + fcp[fm][3]);
            out[(T_STEPS - 1) * BATCH + bo + fm] = s + bfc + xO;
        }
    }
}

extern "C" void kernel_launch(void* const* d_in, const int* in_sizes, int n_in,
                              void* d_out, int out_size, void* d_ws, size_t ws_size,
                              hipStream_t stream) {
    (void)in_sizes; (void)n_in; (void)out_size; (void)ws_size;
    const float* x    = (const float*)d_in[0];
    const float* W_ih = (const float*)d_in[1];
    const float* W_hh = (const float*)d_in[2];
    const float* b_ih = (const float*)d_in[3];
    const float* b_hh = (const float*)d_in[4];
    const float* W_fc = (const float*)d_in[5];
    const float* b_fc = (const float*)d_in[6];
    float* out = (float*)d_out;
    u32* wpk = (u32*)d_ws;                          // 384*48 u32 = 73728 B

    prepack_kernel<<<dim3((384 * 48 + 255) / 256), dim3(256), 0, stream>>>(W_hh, wpk);

    lstm_mfma_kernel<<<dim3(NBLK), dim3(448), 0, stream>>>(
        x, W_ih, b_ih, b_hh, W_fc, b_fc, (const u32x4*)wpk, out);
}